// Round 10
// baseline (488.791 us; speedup 1.0000x reference)
//
#include <hip/hip_runtime.h>
#include <hip/hip_bf16.h>
#include <math.h>

// Qwen3.5 attention block, bf16-MFMA everywhere.
// cvt(hs), transpose_cvt(w_qkv) -> gemm_bf16(QKV, BK=64) -> vt_transpose ->
// norm_rope_cvt (wave-parallel) -> flash_attn_mfma v11 (split-K=2, partial
// O/l into dead ws regions) -> attn_combine -> transpose_cvt(w_o) -> gemm.

namespace {
constexpr int kT   = 4096;
constexpr int kHid = 2048;
constexpr int kH   = 16;
constexpr int kHkv = 2;
constexpr int kD   = 128;
constexpr int kNqkv = (2 * kH + 2 * kHkv) * kD;  // 4608 floats per row
constexpr int kQsz  = 2 * kH * kD;               // 4096
constexpr int kRowU = kNqkv * 2;                 // 9216 ushorts per row
constexpr float kEps = 1e-6f;
constexpr float kScale = 0.08838834764831845f;   // 128^-0.5
}

typedef __attribute__((ext_vector_type(8))) short short8;
typedef __attribute__((ext_vector_type(4))) float floatx4;

__device__ inline unsigned short f2bf(float x) {
  unsigned u = __float_as_uint(x);
  u = (u + 0x7fffu + ((u >> 16) & 1u)) >> 16;
  return (unsigned short)u;
}

__device__ inline float bf2f(unsigned short u) {
  return __uint_as_float((unsigned)u << 16);
}

__device__ inline void gload_lds16(const void* g, void* l) {
  typedef const __attribute__((address_space(1))) unsigned GQ;
  typedef __attribute__((address_space(3))) unsigned LQ;
  __builtin_amdgcn_global_load_lds((GQ*)g, (LQ*)l, 16, 0, 0);
}

// ---- fp32 -> bf16 elementwise ----
__global__ __launch_bounds__(256)
void cvt_bf16(const float* __restrict__ in, unsigned short* __restrict__ out,
              long nelem) {
  long i = ((long)blockIdx.x * 256 + threadIdx.x) * 4;
  if (i >= nelem) return;
  float4 v = *(const float4*)(in + i);
  unsigned long long p = (unsigned long long)f2bf(v.x) |
                         ((unsigned long long)f2bf(v.y) << 16) |
                         ((unsigned long long)f2bf(v.z) << 32) |
                         ((unsigned long long)f2bf(v.w) << 48);
  *(unsigned long long*)(out + i) = p;
}

// ---- fp32 [R][C] -> bf16 [C][R] tiled transpose ----
__global__ __launch_bounds__(256)
void transpose_cvt(const float* __restrict__ in, unsigned short* __restrict__ out,
                   int R, int C) {
  __shared__ float t[32][33];
  const int bx = blockIdx.x * 32;
  const int by = blockIdx.y * 32;
  const int x = threadIdx.x & 31, y = threadIdx.x >> 5;
#pragma unroll
  for (int j = 0; j < 4; ++j)
    t[y * 4 + j][x] = in[(long)(by + y * 4 + j) * C + bx + x];
  __syncthreads();
#pragma unroll
  for (int j = 0; j < 4; ++j)
    out[(long)(bx + y * 4 + j) * R + by + x] = f2bf(t[x][y * 4 + j]);
}

// ---- V^T pre-transpose: qkv fp32 V (rows t, 256 cols) -> VtG bf16 [256][T] ----
__global__ __launch_bounds__(256)
void vt_transpose(const float* __restrict__ qkv, unsigned short* __restrict__ VtG) {
  __shared__ float t[32][33];
  const int t0 = blockIdx.x * 32;
  const int c0 = blockIdx.y * 32;
  const int x = threadIdx.x & 31, y = threadIdx.x >> 5;
#pragma unroll
  for (int j = 0; j < 4; ++j)
    t[y * 4 + j][x] = qkv[(long)(t0 + y * 4 + j) * kNqkv + 4352 + c0 + x];
  __syncthreads();
#pragma unroll
  for (int j = 0; j < 4; ++j)
    VtG[(long)(c0 + y * 4 + j) * kT + t0 + x] = f2bf(t[x][y * 4 + j]);
}

// ---- C[M,N] fp32 = A[M,K]bf16 @ Bt[N,K]bf16^T. 128x128 tile, BK=64. ----
__global__ __launch_bounds__(256)
void gemm_bf16(const unsigned short* __restrict__ A,
               const unsigned short* __restrict__ Bt, float* __restrict__ C,
               int M, int N, int K) {
  __shared__ __align__(16) unsigned short As[128 * 64];
  __shared__ __align__(16) unsigned short Bs[128 * 64];
  const int tid = threadIdx.x;
  const int lane = tid & 63;
  const int w = tid >> 6;
  const int wr = w >> 1, wc = w & 1;
  const int n = lane & 15;
  const int quad = lane >> 4;
  const long bm = (long)blockIdx.x * 128, bn = (long)blockIdx.y * 128;

  floatx4 acc[4][4];
  floatx4 zero = {0.f, 0.f, 0.f, 0.f};
#pragma unroll
  for (int a = 0; a < 4; ++a)
#pragma unroll
    for (int b = 0; b < 4; ++b) acc[a][b] = zero;

  for (int k0 = 0; k0 < K; k0 += 64) {
    __syncthreads();
#pragma unroll
    for (int it = 0; it < 4; ++it) {
      int ci = it * 256 + tid;            // 16B chunk id 0..1023
      int r = ci >> 3, c = ci & 7;
      int cg = c ^ (r & 7);               // global chunk for this slot
      gload_lds16(A + (bm + r) * (long)K + k0 + cg * 8, As + (it * 256 + w * 64) * 8);
      gload_lds16(Bt + (bn + r) * (long)K + k0 + cg * 8, Bs + (it * 256 + w * 64) * 8);
    }
    __syncthreads();

#pragma unroll
    for (int ks = 0; ks < 2; ++ks) {
      short8 af[4], bf[4];
#pragma unroll
      for (int a = 0; a < 4; ++a) {
        int m = wr * 64 + a * 16 + n;
        af[a] = *(const short8*)(As + m * 64 + ((4 * ks + quad) ^ (m & 7)) * 8);
      }
#pragma unroll
      for (int b = 0; b < 4; ++b) {
        int nn = wc * 64 + b * 16 + n;
        bf[b] = *(const short8*)(Bs + nn * 64 + ((4 * ks + quad) ^ (nn & 7)) * 8);
      }
#pragma unroll
      for (int a = 0; a < 4; ++a)
#pragma unroll
        for (int b = 0; b < 4; ++b)
          acc[a][b] = __builtin_amdgcn_mfma_f32_16x16x32_bf16(af[a], bf[b], acc[a][b], 0, 0, 0);
    }
  }
#pragma unroll
  for (int a = 0; a < 4; ++a)
#pragma unroll
    for (int b = 0; b < 4; ++b)
#pragma unroll
      for (int r = 0; r < 4; ++r)
        C[(bm + wr * 64 + a * 16 + quad * 4 + r) * (long)N + bn + wc * 64 + b * 16 + n] =
            acc[a][b][r];
}

// ------- RMSNorm + RoPE + bf16 pack (q,k), wave-parallel, barrier-free -------
__global__ __launch_bounds__(256)
void norm_rope_cvt(float* qkv, const float* __restrict__ cosb,
                   const float* __restrict__ sinb, const float* __restrict__ qw,
                   const float* __restrict__ kw) {
  unsigned short* qkvu = (unsigned short*)qkv;
  const int lane = threadIdx.x & 63;
  const int wslot = blockIdx.x * 4 + (threadIdx.x >> 6);
  const int nslots = gridDim.x * 4;
  for (int task = wslot; task < kT * 18; task += nslots) {
    const int t = task / 18;
    const int h = task % 18;
    const bool isq = (h < kH);
    const long base = (long)t * kNqkv + (isq ? h * 2 * kD : kQsz + (h - kH) * kD);
    float xlo = qkv[base + lane];
    float xhi = qkv[base + 64 + lane];
    float v = xlo * xlo + xhi * xhi;
#pragma unroll
    for (int off = 1; off < 64; off <<= 1) v += __shfl_xor(v, off, 64);
    float rms = rsqrtf(v * (1.0f / kD) + kEps);
    const float* wv = isq ? qw : kw;
    float nlo = xlo * rms * wv[lane];
    float nhi = xhi * rms * wv[64 + lane];
    float clo = cosb[t * kD + lane], chi = cosb[t * kD + 64 + lane];
    float slo = sinb[t * kD + lane], shi = sinb[t * kD + 64 + lane];
    float rlo = nlo * clo - nhi * slo;   // rot(lo) = -x[l+64]
    float rhi = nhi * chi + nlo * shi;   // rot(hi) = +x[l]
    if (isq) {
      float glo = qkv[base + kD + lane];
      float ghi = qkv[base + kD + 64 + lane];
      qkv[base + kD + lane] = 1.0f / (1.0f + __expf(-glo));
      qkv[base + kD + 64 + lane] = 1.0f / (1.0f + __expf(-ghi));
      qkvu[(long)t * kRowU + 512 * h + lane] = f2bf(rlo);
      qkvu[(long)t * kRowU + 512 * h + 64 + lane] = f2bf(rhi);
    } else {
      qkvu[(long)t * kRowU + 8192 + 256 * (h - kH) + lane] = f2bf(rlo);
      qkvu[(long)t * kRowU + 8192 + 256 * (h - kH) + 64 + lane] = f2bf(rhi);
    }
  }
}

// ---------------- bf16 MFMA flash attention v11 (split-K=2) ----------------
// v10 per-tile structure EXACTLY (2 barriers/tile, dedicated Ps). Softmax here
// has NO online max (exp absolute, |s*scale|<=11.3) -> partials are LINEAR:
// O = Oa+Ob, l = la+lb. Each (h, q-tile) is computed by TWO blocks:
// half 0: kn in [0, bm]; half 1: kn in [bm+1, 2bm+1]. Max serial chain
// 64 -> 32 tiles; grid 512 -> 1024; balanced LPT (bm descending).
// Partials go to provably-dead ws regions (zero extra workspace):
//   Oa bf16 -> og region (hsb dead after QKV gemm), layout = final og.
//   Ob bf16 -> dead q-fp32 half-cols: ushort t*kRowU + 512h + 128 + d.
//   la/lb fp32 -> dead V-fp32 cols: float t*kNqkv + 4352+h / 4368+h.
__global__ __launch_bounds__(256)
void flash_attn_mfma(const unsigned short* qkvu, float* qkvf,
                     const unsigned short* VtG, unsigned short* __restrict__ ogp) {
  __shared__ __align__(16) unsigned short Ks[64 * 128];  // K tile (swizzled)
  __shared__ __align__(16) unsigned short Vt[128 * 64];  // V^T tile (swizzled)
  __shared__ __align__(16) unsigned short Ps[128 * 64];  // P tile (row-swizzled)

  const int tid = threadIdx.x;
  const int lane = tid & 63;
  const int w = tid >> 6;
  const int n = lane & 15;
  const int quad = lane >> 4;
  const int g = blockIdx.x;
  const int h = g & 15;
  const int gi = g >> 4;                 // 0..63
  const int bm = 31 - (gi >> 1);         // heavy-first
  const int half = gi & 1;
  const int hk = h >> 3;
  const int q0 = bm * 128;

  short8 qf[2][4];
#pragma unroll
  for (int mt = 0; mt < 2; ++mt) {
    const unsigned short* qrow =
        qkvu + (long)(q0 + 32 * w + 16 * mt + n) * kRowU + 512 * h;
#pragma unroll
    for (int ks = 0; ks < 4; ++ks)
      qf[mt][ks] = *(const short8*)(qrow + 32 * ks + 8 * quad);
  }
  short8 lfrag;  // B-frag: col 0 = ones -> row-sum accumulator
  {
    short o = (n == 0) ? (short)0x3F80 : (short)0;
    lfrag = (short8){o, o, o, o, o, o, o, o};
  }

  floatx4 O[2][8];
  floatx4 Ol[2];
  floatx4 zero = {0.f, 0.f, 0.f, 0.f};
#pragma unroll
  for (int mt = 0; mt < 2; ++mt) {
    Ol[mt] = zero;
#pragma unroll
    for (int dt = 0; dt < 8; ++dt) O[mt][dt] = zero;
  }

  const int kn0 = half ? (bm + 1) : 0;
  const int kn1 = half ? (2 * bm + 1) : bm;
  for (int kn = kn0; kn <= kn1; ++kn) {
    __syncthreads();  // (1) prev QK+PV reads done before restage
    // stage K: 64 rows x 128 d, chunk swizzle c ^ (r&15)
#pragma unroll
    for (int it = 0; it < 4; ++it) {
      int pc = (w * 4 + it) * 64 + lane;
      int r = pc >> 4, c = pc & 15;
      int lc = c ^ (r & 15);
      gload_lds16(qkvu + (long)(kn * 64 + r) * kRowU + 8192 + 256 * hk + 8 * lc,
                  Ks + (w * 4 + it) * 512);
    }
    // stage V^T: 128 rows (d) x 64 keys, chunk swizzle c ^ (d&7)
#pragma unroll
    for (int it = 0; it < 4; ++it) {
      int pc = (w * 4 + it) * 64 + lane;
      int d = pc >> 3, c = pc & 7;
      int lc = c ^ (d & 7);
      gload_lds16(VtG + (long)hk * (128 * kT) + (long)d * kT + kn * 64 + 8 * lc,
                  Vt + (w * 4 + it) * 512);
    }
    __syncthreads();  // (2) staging complete

    // S = Q K^T  (kf shared across both m-tiles)
    floatx4 S[2][4];
#pragma unroll
    for (int mt = 0; mt < 2; ++mt)
#pragma unroll
      for (int ct = 0; ct < 4; ++ct) S[mt][ct] = zero;
#pragma unroll
    for (int ks = 0; ks < 4; ++ks) {
#pragma unroll
      for (int ct = 0; ct < 4; ++ct) {
        int row = 16 * ct + n;
        short8 kf = *(const short8*)(Ks + row * 128 + ((4 * ks + quad) ^ n) * 8);
        S[0][ct] = __builtin_amdgcn_mfma_f32_16x16x32_bf16(qf[0][ks], kf, S[0][ct], 0, 0, 0);
        S[1][ct] = __builtin_amdgcn_mfma_f32_16x16x32_bf16(qf[1][ks], kf, S[1][ct], 0, 0, 0);
      }
    }
    // no barrier: Ps is a separate buffer, each wave's rows are private

    // p = exp(s*scale); write Ps (128 rows x 64 cols, row-swizzled)
    const bool needmask = (kn >= 2 * bm);
    const int jbase = (kn - 2 * bm) * 64;
    const int hi = n >> 3, lo = n & 7;
#pragma unroll
    for (int mt = 0; mt < 2; ++mt) {
#pragma unroll
      for (int r = 0; r < 4; ++r) {
        int prow = 32 * w + 16 * mt + quad * 4 + r;
        float p0 = __expf(S[mt][0][r] * kScale);
        float p1 = __expf(S[mt][1][r] * kScale);
        float p2 = __expf(S[mt][2][r] * kScale);
        float p3 = __expf(S[mt][3][r] * kScale);
        if (needmask) {
          if (jbase + n > prow) p0 = 0.f;
          if (jbase + 16 + n > prow) p1 = 0.f;
          if (jbase + 32 + n > prow) p2 = 0.f;
          if (jbase + 48 + n > prow) p3 = 0.f;
        }
        int sw = prow & 7;
        Ps[prow * 64 + (((0 + hi) ^ sw) << 3) + lo] = f2bf(p0);
        Ps[prow * 64 + (((2 + hi) ^ sw) << 3) + lo] = f2bf(p1);
        Ps[prow * 64 + (((4 + hi) ^ sw) << 3) + lo] = f2bf(p2);
        Ps[prow * 64 + (((6 + hi) ^ sw) << 3) + lo] = f2bf(p3);
      }
    }
    __asm__ volatile("s_waitcnt lgkmcnt(0)" ::: "memory");  // own-wave Ps visible

    // O += P V ; Ol += P @ ones  (vf shared across both m-tiles)
#pragma unroll
    for (int ks = 0; ks < 2; ++ks) {
      int r0 = 32 * w + n, r1 = 32 * w + 16 + n;
      short8 pf0 = *(const short8*)(Ps + r0 * 64 + (((4 * ks + quad) ^ (r0 & 7)) << 3));
      short8 pf1 = *(const short8*)(Ps + r1 * 64 + (((4 * ks + quad) ^ (r1 & 7)) << 3));
      Ol[0] = __builtin_amdgcn_mfma_f32_16x16x32_bf16(pf0, lfrag, Ol[0], 0, 0, 0);
      Ol[1] = __builtin_amdgcn_mfma_f32_16x16x32_bf16(pf1, lfrag, Ol[1], 0, 0, 0);
#pragma unroll
      for (int dt = 0; dt < 8; ++dt) {
        int d = 16 * dt + n;
        short8 vf = *(const short8*)(Vt + d * 64 + (((4 * ks + quad) ^ (d & 7)) << 3));
        O[0][dt] = __builtin_amdgcn_mfma_f32_16x16x32_bf16(pf0, vf, O[0][dt], 0, 0, 0);
        O[1][dt] = __builtin_amdgcn_mfma_f32_16x16x32_bf16(pf1, vf, O[1][dt], 0, 0, 0);
      }
    }
  }

  // epilogue: write PARTIAL O (bf16, un-normalized, un-gated) + partial l
  unsigned short* obuf = half ? (unsigned short*)qkvf : ogp;
#pragma unroll
  for (int mt = 0; mt < 2; ++mt) {
#pragma unroll
    for (int r = 0; r < 4; ++r) {
      int row = q0 + 32 * w + 16 * mt + quad * 4 + r;
      if (n == 0)  // lanes 0/16/32/48 hold this row's l in Ol[mt][r]
        qkvf[(long)row * kNqkv + (half ? 4368 : 4352) + h] = Ol[mt][r];
      long base = half ? ((long)row * kRowU + 512 * h + 128)
                       : ((long)row * kHid + 128 * h);
#pragma unroll
      for (int dt = 0; dt < 8; ++dt)
        obuf[base + 16 * dt + n] = f2bf(O[mt][dt][r]);
    }
  }
}

// ---- combine: O = (Oa+Ob)/(la+lb) * gate -> og bf16 ----
__global__ __launch_bounds__(256)
void attn_combine(float* qkvf, unsigned short* og) {
  const unsigned short* qkvu = (const unsigned short*)qkvf;
  const int tid = threadIdx.x;
  const int row = blockIdx.x * 16 + (tid >> 4);   // (t,h) index, 0..65535
  const int d0 = (tid & 15) * 8;
  const int t = row >> 4, h = row & 15;
  short8 oa = *(const short8*)(og + (long)t * kHid + 128 * h + d0);
  short8 ob = *(const short8*)(qkvu + (long)t * kRowU + 512 * h + 128 + d0);
  float la = qkvf[(long)t * kNqkv + 4352 + h];
  float lb = qkvf[(long)t * kNqkv + 4368 + h];
  float inv = 1.0f / (la + lb);
  const float* gate = qkvf + (long)t * kNqkv + 256 * h + 128 + d0;
  short8 res;
#pragma unroll
  for (int j = 0; j < 8; ++j) {
    float o = bf2f((unsigned short)oa[j]) + bf2f((unsigned short)ob[j]);
    res[j] = (short)f2bf(o * inv * gate[j]);
  }
  *(short8*)(og + (long)t * kHid + 128 * h + d0) = res;
}

extern "C" void kernel_launch(void* const* d_in, const int* in_sizes, int n_in,
                              void* d_out, int out_size, void* d_ws, size_t ws_size,
                              hipStream_t stream) {
  (void)in_sizes; (void)n_in; (void)out_size; (void)ws_size;
  const float* hs   = (const float*)d_in[0];
  const float* cosb = (const float*)d_in[1];
  const float* sinb = (const float*)d_in[2];
  const float* wqkv = (const float*)d_in[3];
  const float* wo   = (const float*)d_in[4];
  const float* qw   = (const float*)d_in[5];
  const float* kw   = (const float*)d_in[6];
  float* out = (float*)d_out;

  char* ws = (char*)d_ws;
  float* qkv = (float*)ws;                                    // 75.5 MB fp32
  unsigned short* hsb = (unsigned short*)(ws + 75497472);     // 16.8 MB (aliases og)
  unsigned short* og  = hsb;                                  // written after hsb dead
  unsigned short* wt  = (unsigned short*)(ws + 92274688);     // 18.9 MB shared
  unsigned short* VtG = wt;  // aliases dead w_qkv^T during flash (w_o^T written after)

  cvt_bf16<<<dim3(8192), 256, 0, stream>>>(hs, hsb, (long)kT * kHid);
  transpose_cvt<<<dim3(kNqkv / 32, kHid / 32), 256, 0, stream>>>(wqkv, wt, kHid, kNqkv);
  gemm_bf16<<<dim3(kT / 128, kNqkv / 128), 256, 0, stream>>>(hsb, wt, qkv, kT, kNqkv, kHid);
  vt_transpose<<<dim3(kT / 32, 8), 256, 0, stream>>>(qkv, VtG);
  norm_rope_cvt<<<dim3(2304), 256, 0, stream>>>(qkv, cosb, sinb, qw, kw);
  flash_attn_mfma<<<dim3(kT / 128 * kH * 2), 256, 0, stream>>>((const unsigned short*)qkv, qkv, VtG, og);
  attn_combine<<<dim3(kT * kH / 16), 256, 0, stream>>>(qkv, og);
  transpose_cvt<<<dim3(kHid / 32, kHid / 32), 256, 0, stream>>>(wo, wt, kHid, kHid);
  gemm_bf16<<<dim3(kT / 128, kHid / 128), 256, 0, stream>>>(og, wt, out, kHid == 2048 ? kT : kT, kHid, kHid);
}

// Round 11
// 482.841 us; speedup vs baseline: 1.0123x; 1.0123x over previous
//
#include <hip/hip_runtime.h>
#include <hip/hip_bf16.h>
#include <math.h>

// Qwen3.5 attention block, bf16-MFMA everywhere.
// cvt(hs), transpose_cvt(w_qkv) -> gemm_bf16(QKV, XCD-band swizzle) ->
// vt_transpose -> norm_rope_cvt (wave-parallel) ->
// flash_attn_mfma v10 (best measured: 166.7us) ->
// transpose_cvt(w_o) -> gemm_bf16(out, swizzled).

namespace {
constexpr int kT   = 4096;
constexpr int kHid = 2048;
constexpr int kH   = 16;
constexpr int kHkv = 2;
constexpr int kD   = 128;
constexpr int kNqkv = (2 * kH + 2 * kHkv) * kD;  // 4608 floats per row
constexpr int kQsz  = 2 * kH * kD;               // 4096
constexpr int kRowU = kNqkv * 2;                 // 9216 ushorts per row
constexpr float kEps = 1e-6f;
constexpr float kScale = 0.08838834764831845f;   // 128^-0.5
}

typedef __attribute__((ext_vector_type(8))) short short8;
typedef __attribute__((ext_vector_type(4))) float floatx4;

__device__ inline unsigned short f2bf(float x) {
  unsigned u = __float_as_uint(x);
  u = (u + 0x7fffu + ((u >> 16) & 1u)) >> 16;
  return (unsigned short)u;
}

__device__ inline void gload_lds16(const void* g, void* l) {
  typedef const __attribute__((address_space(1))) unsigned GQ;
  typedef __attribute__((address_space(3))) unsigned LQ;
  __builtin_amdgcn_global_load_lds((GQ*)g, (LQ*)l, 16, 0, 0);
}

// ---- fp32 -> bf16 elementwise ----
__global__ __launch_bounds__(256)
void cvt_bf16(const float* __restrict__ in, unsigned short* __restrict__ out,
              long nelem) {
  long i = ((long)blockIdx.x * 256 + threadIdx.x) * 4;
  if (i >= nelem) return;
  float4 v = *(const float4*)(in + i);
  unsigned long long p = (unsigned long long)f2bf(v.x) |
                         ((unsigned long long)f2bf(v.y) << 16) |
                         ((unsigned long long)f2bf(v.z) << 32) |
                         ((unsigned long long)f2bf(v.w) << 48);
  *(unsigned long long*)(out + i) = p;
}

// ---- fp32 [R][C] -> bf16 [C][R] tiled transpose ----
__global__ __launch_bounds__(256)
void transpose_cvt(const float* __restrict__ in, unsigned short* __restrict__ out,
                   int R, int C) {
  __shared__ float t[32][33];
  const int bx = blockIdx.x * 32;
  const int by = blockIdx.y * 32;
  const int x = threadIdx.x & 31, y = threadIdx.x >> 5;
#pragma unroll
  for (int j = 0; j < 4; ++j)
    t[y * 4 + j][x] = in[(long)(by + y * 4 + j) * C + bx + x];
  __syncthreads();
#pragma unroll
  for (int j = 0; j < 4; ++j)
    out[(long)(bx + y * 4 + j) * R + by + x] = f2bf(t[x][y * 4 + j]);
}

// ---- V^T pre-transpose: qkv fp32 V (rows t, 256 cols) -> VtG bf16 [256][T] ----
__global__ __launch_bounds__(256)
void vt_transpose(const float* __restrict__ qkv, unsigned short* __restrict__ VtG) {
  __shared__ float t[32][33];
  const int t0 = blockIdx.x * 32;
  const int c0 = blockIdx.y * 32;
  const int x = threadIdx.x & 31, y = threadIdx.x >> 5;
#pragma unroll
  for (int j = 0; j < 4; ++j)
    t[y * 4 + j][x] = qkv[(long)(t0 + y * 4 + j) * kNqkv + 4352 + c0 + x];
  __syncthreads();
#pragma unroll
  for (int j = 0; j < 4; ++j)
    VtG[(long)(c0 + y * 4 + j) * kT + t0 + x] = f2bf(t[x][y * 4 + j]);
}

// ---- C[M,N] fp32 = A[M,K]bf16 @ Bt[N,K]bf16^T. 128x128 tile, BK=64. ----
// XCD-band swizzle: dispatch order (bx fastest) makes consecutive blocks
// cycle all 32 A-panels (16MB) -> A thrashes each XCD's 4MB L2. Remap so
// XCD x owns a contiguous band of 4 M-tiles: its A working set = 2MB,
// L2-resident; B streams. Bijective for nbx=32, nwg%8==0 (both GEMMs).
__global__ __launch_bounds__(256)
void gemm_bf16(const unsigned short* __restrict__ A,
               const unsigned short* __restrict__ Bt, float* __restrict__ C,
               int M, int N, int K) {
  __shared__ __align__(16) unsigned short As[128 * 64];
  __shared__ __align__(16) unsigned short Bs[128 * 64];
  const int tid = threadIdx.x;
  const int lane = tid & 63;
  const int w = tid >> 6;
  const int wr = w >> 1, wc = w & 1;
  const int n = lane & 15;
  const int quad = lane >> 4;

  int bx = blockIdx.x, by = blockIdx.y;
  const int nbx = gridDim.x, nby = gridDim.y;
  if (nbx == 32 && ((nbx * nby) & 7) == 0) {
    int lin = bx + nbx * by;        // dispatch-linear id (x fastest)
    int xcd = lin & 7, s = lin >> 3;
    bx = 4 * xcd + (s & 3);
    by = s >> 2;
  }
  const long bm = (long)bx * 128, bn = (long)by * 128;

  floatx4 acc[4][4];
  floatx4 zero = {0.f, 0.f, 0.f, 0.f};
#pragma unroll
  for (int a = 0; a < 4; ++a)
#pragma unroll
    for (int b = 0; b < 4; ++b) acc[a][b] = zero;

  for (int k0 = 0; k0 < K; k0 += 64) {
    __syncthreads();
#pragma unroll
    for (int it = 0; it < 4; ++it) {
      int ci = it * 256 + tid;            // 16B chunk id 0..1023
      int r = ci >> 3, c = ci & 7;
      int cg = c ^ (r & 7);               // global chunk for this slot
      gload_lds16(A + (bm + r) * (long)K + k0 + cg * 8, As + (it * 256 + w * 64) * 8);
      gload_lds16(Bt + (bn + r) * (long)K + k0 + cg * 8, Bs + (it * 256 + w * 64) * 8);
    }
    __syncthreads();

#pragma unroll
    for (int ks = 0; ks < 2; ++ks) {
      short8 af[4], bf[4];
#pragma unroll
      for (int a = 0; a < 4; ++a) {
        int m = wr * 64 + a * 16 + n;
        af[a] = *(const short8*)(As + m * 64 + ((4 * ks + quad) ^ (m & 7)) * 8);
      }
#pragma unroll
      for (int b = 0; b < 4; ++b) {
        int nn = wc * 64 + b * 16 + n;
        bf[b] = *(const short8*)(Bs + nn * 64 + ((4 * ks + quad) ^ (nn & 7)) * 8);
      }
#pragma unroll
      for (int a = 0; a < 4; ++a)
#pragma unroll
        for (int b = 0; b < 4; ++b)
          acc[a][b] = __builtin_amdgcn_mfma_f32_16x16x32_bf16(af[a], bf[b], acc[a][b], 0, 0, 0);
    }
  }
#pragma unroll
  for (int a = 0; a < 4; ++a)
#pragma unroll
    for (int b = 0; b < 4; ++b)
#pragma unroll
      for (int r = 0; r < 4; ++r)
        C[(bm + wr * 64 + a * 16 + quad * 4 + r) * (long)N + bn + wc * 64 + b * 16 + n] =
            acc[a][b][r];
}

// ------- RMSNorm + RoPE + bf16 pack (q,k), wave-parallel, barrier-free -------
__global__ __launch_bounds__(256)
void norm_rope_cvt(float* qkv, const float* __restrict__ cosb,
                   const float* __restrict__ sinb, const float* __restrict__ qw,
                   const float* __restrict__ kw) {
  unsigned short* qkvu = (unsigned short*)qkv;
  const int lane = threadIdx.x & 63;
  const int wslot = blockIdx.x * 4 + (threadIdx.x >> 6);
  const int nslots = gridDim.x * 4;
  for (int task = wslot; task < kT * 18; task += nslots) {
    const int t = task / 18;
    const int h = task % 18;
    const bool isq = (h < kH);
    const long base = (long)t * kNqkv + (isq ? h * 2 * kD : kQsz + (h - kH) * kD);
    float xlo = qkv[base + lane];
    float xhi = qkv[base + 64 + lane];
    float v = xlo * xlo + xhi * xhi;
#pragma unroll
    for (int off = 1; off < 64; off <<= 1) v += __shfl_xor(v, off, 64);
    float rms = rsqrtf(v * (1.0f / kD) + kEps);
    const float* wv = isq ? qw : kw;
    float nlo = xlo * rms * wv[lane];
    float nhi = xhi * rms * wv[64 + lane];
    float clo = cosb[t * kD + lane], chi = cosb[t * kD + 64 + lane];
    float slo = sinb[t * kD + lane], shi = sinb[t * kD + 64 + lane];
    float rlo = nlo * clo - nhi * slo;   // rot(lo) = -x[l+64]
    float rhi = nhi * chi + nlo * shi;   // rot(hi) = +x[l]
    if (isq) {
      float glo = qkv[base + kD + lane];
      float ghi = qkv[base + kD + 64 + lane];
      qkv[base + kD + lane] = 1.0f / (1.0f + __expf(-glo));
      qkv[base + kD + 64 + lane] = 1.0f / (1.0f + __expf(-ghi));
      qkvu[(long)t * kRowU + 512 * h + lane] = f2bf(rlo);
      qkvu[(long)t * kRowU + 512 * h + 64 + lane] = f2bf(rhi);
    } else {
      qkvu[(long)t * kRowU + 8192 + 256 * (h - kH) + lane] = f2bf(rlo);
      qkvu[(long)t * kRowU + 8192 + 256 * (h - kH) + 64 + lane] = f2bf(rhi);
    }
  }
}

// ---------------- bf16 MFMA flash attention v10 (best: 166.7us) -------------
// v3 structure + dedicated Ps buffer (barrier (3) removed; 2 barriers/tile).
__global__ __launch_bounds__(256)
void flash_attn_mfma(const unsigned short* qkvu, const float* qkvf,
                     const unsigned short* VtG, unsigned short* __restrict__ og) {
  __shared__ __align__(16) unsigned short Ks[64 * 128];  // K tile (swizzled)
  __shared__ __align__(16) unsigned short Vt[128 * 64];  // V^T tile (swizzled)
  __shared__ __align__(16) unsigned short Ps[128 * 64];  // P tile (row-swizzled)

  const int tid = threadIdx.x;
  const int lane = tid & 63;
  const int w = tid >> 6;
  const int n = lane & 15;
  const int quad = lane >> 4;
  const int g = blockIdx.x;
  const int h = g & 15;
  const int bm = 31 - (g >> 4);   // heavy-first
  const int hk = h >> 3;
  const int q0 = bm * 128;

  short8 qf[2][4];
#pragma unroll
  for (int mt = 0; mt < 2; ++mt) {
    const unsigned short* qrow =
        qkvu + (long)(q0 + 32 * w + 16 * mt + n) * kRowU + 512 * h;
#pragma unroll
    for (int ks = 0; ks < 4; ++ks)
      qf[mt][ks] = *(const short8*)(qrow + 32 * ks + 8 * quad);
  }
  short8 lfrag;  // B-frag: col 0 = ones -> row-sum accumulator
  {
    short o = (n == 0) ? (short)0x3F80 : (short)0;
    lfrag = (short8){o, o, o, o, o, o, o, o};
  }

  floatx4 O[2][8];
  floatx4 Ol[2];
  floatx4 zero = {0.f, 0.f, 0.f, 0.f};
#pragma unroll
  for (int mt = 0; mt < 2; ++mt) {
    Ol[mt] = zero;
#pragma unroll
    for (int dt = 0; dt < 8; ++dt) O[mt][dt] = zero;
  }

  const int kn_end = 2 * bm + 1;
  for (int kn = 0; kn <= kn_end; ++kn) {
    __syncthreads();  // (1) prev QK+PV reads done before restage
    // stage K: 64 rows x 128 d, chunk swizzle c ^ (r&15)
#pragma unroll
    for (int it = 0; it < 4; ++it) {
      int pc = (w * 4 + it) * 64 + lane;
      int r = pc >> 4, c = pc & 15;
      int lc = c ^ (r & 15);
      gload_lds16(qkvu + (long)(kn * 64 + r) * kRowU + 8192 + 256 * hk + 8 * lc,
                  Ks + (w * 4 + it) * 512);
    }
    // stage V^T: 128 rows (d) x 64 keys, chunk swizzle c ^ (d&7)
#pragma unroll
    for (int it = 0; it < 4; ++it) {
      int pc = (w * 4 + it) * 64 + lane;
      int d = pc >> 3, c = pc & 7;
      int lc = c ^ (d & 7);
      gload_lds16(VtG + (long)hk * (128 * kT) + (long)d * kT + kn * 64 + 8 * lc,
                  Vt + (w * 4 + it) * 512);
    }
    __syncthreads();  // (2) staging complete

    // S = Q K^T  (kf shared across both m-tiles)
    floatx4 S[2][4];
#pragma unroll
    for (int mt = 0; mt < 2; ++mt)
#pragma unroll
      for (int ct = 0; ct < 4; ++ct) S[mt][ct] = zero;
#pragma unroll
    for (int ks = 0; ks < 4; ++ks) {
#pragma unroll
      for (int ct = 0; ct < 4; ++ct) {
        int row = 16 * ct + n;
        short8 kf = *(const short8*)(Ks + row * 128 + ((4 * ks + quad) ^ n) * 8);
        S[0][ct] = __builtin_amdgcn_mfma_f32_16x16x32_bf16(qf[0][ks], kf, S[0][ct], 0, 0, 0);
        S[1][ct] = __builtin_amdgcn_mfma_f32_16x16x32_bf16(qf[1][ks], kf, S[1][ct], 0, 0, 0);
      }
    }
    // no barrier: Ps is a separate buffer, each wave's rows are private

    // p = exp(s*scale); write Ps (128 rows x 64 cols, row-swizzled)
    const bool needmask = (kn >= 2 * bm);
    const int jbase = (kn - 2 * bm) * 64;
    const int hi = n >> 3, lo = n & 7;
#pragma unroll
    for (int mt = 0; mt < 2; ++mt) {
#pragma unroll
      for (int r = 0; r < 4; ++r) {
        int prow = 32 * w + 16 * mt + quad * 4 + r;
        float p0 = __expf(S[mt][0][r] * kScale);
        float p1 = __expf(S[mt][1][r] * kScale);
        float p2 = __expf(S[mt][2][r] * kScale);
        float p3 = __expf(S[mt][3][r] * kScale);
        if (needmask) {
          if (jbase + n > prow) p0 = 0.f;
          if (jbase + 16 + n > prow) p1 = 0.f;
          if (jbase + 32 + n > prow) p2 = 0.f;
          if (jbase + 48 + n > prow) p3 = 0.f;
        }
        int sw = prow & 7;
        Ps[prow * 64 + (((0 + hi) ^ sw) << 3) + lo] = f2bf(p0);
        Ps[prow * 64 + (((2 + hi) ^ sw) << 3) + lo] = f2bf(p1);
        Ps[prow * 64 + (((4 + hi) ^ sw) << 3) + lo] = f2bf(p2);
        Ps[prow * 64 + (((6 + hi) ^ sw) << 3) + lo] = f2bf(p3);
      }
    }
    __asm__ volatile("s_waitcnt lgkmcnt(0)" ::: "memory");  // own-wave Ps visible

    // O += P V ; Ol += P @ ones  (vf shared across both m-tiles)
#pragma unroll
    for (int ks = 0; ks < 2; ++ks) {
      int r0 = 32 * w + n, r1 = 32 * w + 16 + n;
      short8 pf0 = *(const short8*)(Ps + r0 * 64 + (((4 * ks + quad) ^ (r0 & 7)) << 3));
      short8 pf1 = *(const short8*)(Ps + r1 * 64 + (((4 * ks + quad) ^ (r1 & 7)) << 3));
      Ol[0] = __builtin_amdgcn_mfma_f32_16x16x32_bf16(pf0, lfrag, Ol[0], 0, 0, 0);
      Ol[1] = __builtin_amdgcn_mfma_f32_16x16x32_bf16(pf1, lfrag, Ol[1], 0, 0, 0);
#pragma unroll
      for (int dt = 0; dt < 8; ++dt) {
        int d = 16 * dt + n;
        short8 vf = *(const short8*)(Vt + d * 64 + (((4 * ks + quad) ^ (d & 7)) << 3));
        O[0][dt] = __builtin_amdgcn_mfma_f32_16x16x32_bf16(pf0, vf, O[0][dt], 0, 0, 0);
        O[1][dt] = __builtin_amdgcn_mfma_f32_16x16x32_bf16(pf1, vf, O[1][dt], 0, 0, 0);
      }
    }
  }

  // epilogue: l broadcast, normalize, gate, store bf16
#pragma unroll
  for (int mt = 0; mt < 2; ++mt) {
#pragma unroll
    for (int r = 0; r < 4; ++r) {
      float l = __shfl(Ol[mt][r], quad << 4, 64);
      float inv = 1.0f / l;
      int row = q0 + 32 * w + 16 * mt + quad * 4 + r;
#pragma unroll
      for (int dt = 0; dt < 8; ++dt) {
        int col = 16 * dt + n;
        float gte = qkvf[(long)row * kNqkv + 256 * h + 128 + col];
        og[(long)row * kHid + 128 * h + col] = f2bf(O[mt][dt][r] * inv * gte);
      }
    }
  }
}

extern "C" void kernel_launch(void* const* d_in, const int* in_sizes, int n_in,
                              void* d_out, int out_size, void* d_ws, size_t ws_size,
                              hipStream_t stream) {
  (void)in_sizes; (void)n_in; (void)out_size; (void)ws_size;
  const float* hs   = (const float*)d_in[0];
  const float* cosb = (const float*)d_in[1];
  const float* sinb = (const float*)d_in[2];
  const float* wqkv = (const float*)d_in[3];
  const float* wo   = (const float*)d_in[4];
  const float* qw   = (const float*)d_in[5];
  const float* kw   = (const float*)d_in[6];
  float* out = (float*)d_out;

  char* ws = (char*)d_ws;
  float* qkv = (float*)ws;                                    // 75.5 MB fp32
  unsigned short* hsb = (unsigned short*)(ws + 75497472);     // 16.8 MB (aliases og)
  unsigned short* og  = hsb;                                  // written after hsb dead
  unsigned short* wt  = (unsigned short*)(ws + 92274688);     // 18.9 MB shared
  unsigned short* VtG = wt;  // aliases dead w_qkv^T during flash (w_o^T written after)

  cvt_bf16<<<dim3(8192), 256, 0, stream>>>(hs, hsb, (long)kT * kHid);
  transpose_cvt<<<dim3(kNqkv / 32, kHid / 32), 256, 0, stream>>>(wqkv, wt, kHid, kNqkv);
  gemm_bf16<<<dim3(kT / 128, kNqkv / 128), 256, 0, stream>>>(hsb, wt, qkv, kT, kNqkv, kHid);
  vt_transpose<<<dim3(kT / 32, 8), 256, 0, stream>>>(qkv, VtG);
  norm_rope_cvt<<<dim3(2304), 256, 0, stream>>>(qkv, cosb, sinb, qw, kw);
  flash_attn_mfma<<<dim3(kT / 128 * kH), 256, 0, stream>>>((const unsigned short*)qkv, qkv, VtG, og);
  transpose_cvt<<<dim3(kHid / 32, kHid / 32), 256, 0, stream>>>(wo, wt, kHid, kHid);
  gemm_bf16<<<dim3(kT / 128, kHid / 128), 256, 0, stream>>>(og, wt, out, kT, kHid, kHid);
}